// Round 1
// baseline (943.198 us; speedup 1.0000x reference)
//
#include <hip/hip_runtime.h>

#define NSTR 8
#define DM 2048
#define NK 120
#define NKP 128
#define TM 128      // positions per workgroup (mean_proj)
#define DSLICE 256  // K-slice per workgroup (split-K over 8 slices)
#define SD 64       // LDS sub-tile depth

// ---------------- kernel 1: zero the z accumulator (8192*128 floats = 4 MB) --
__global__ void zero_ws(float4* z4) {
    z4[(size_t)blockIdx.x * 256 + threadIdx.x] = make_float4(0.f, 0.f, 0.f, 0.f);
}

// ---------------- kernel 2: fused mean-over-streams + projection GEMM --------
// grid 512 = 64 position-tiles x 8 K-slices; block 256; 2 wg/CU.
// Each thread owns an 8p x 8k fp32 accumulator tile (1 B LDS per MAC).
__global__ __launch_bounds__(256, 2)
void mean_proj(const float* __restrict__ streams, const float* __restrict__ W,
               float* __restrict__ z) {
    // [row][16 chunks of 16B], chunk index XOR-swizzled by (row>>3) so that
    // staging writes (dq-fast) and GEMM reads (row-octet-strided) are both
    // <=2-way bank conflicted.
    __shared__ float4 sxa[TM * 16];   // 32 KB: mean(streams) tile [128 p][64 d]
    __shared__ float4 sw[NKP * 16];   // 32 KB: W tile            [128 k][64 d]

    const int t = threadIdx.x;
    const int bid = blockIdx.x;
    const int slice = bid >> 6;   // 0..7  K-slice
    const int ptile = bid & 63;   // 0..63 position tile
    const int pos0 = ptile * TM;
    const int typ = t >> 4;       // p-octet: p = typ*8 + i
    const int txk = t & 15;       // k-octet: k = txk*8 + j

    float acc[8][8];
#pragma unroll
    for (int i = 0; i < 8; ++i)
#pragma unroll
        for (int j = 0; j < 8; ++j) acc[i][j] = 0.f;

    for (int sub = 0; sub < 4; ++sub) {
        const int ds0 = slice * DSLICE + sub * SD;

        // ---- stage xa = mean over 8 streams (coalesced: 16 lanes = 256 B) ----
#pragma unroll
        for (int r = 0; r < 8; ++r) {
            const int item = t + 256 * r;
            const int p = item >> 4;      // 0..127
            const int dq = item & 15;     // 0..15
            const float4* src = (const float4*)(streams
                + (size_t)(pos0 + p) * NSTR * DM + ds0 + dq * 4);
            float4 v = src[0];
#pragma unroll
            for (int n = 1; n < 8; ++n) {
                const float4 u = src[n * (DM / 4)];
                v.x += u.x; v.y += u.y; v.z += u.z; v.w += u.w;
            }
            v.x *= 0.125f; v.y *= 0.125f; v.z *= 0.125f; v.w *= 0.125f;
            sxa[p * 16 + (dq ^ (p >> 3))] = v;
        }
        // ---- stage W slice (rows 120..127 zero-padded) ----
#pragma unroll
        for (int r = 0; r < 8; ++r) {
            const int item = t + 256 * r;
            const int k = item >> 4;
            const int dq = item & 15;
            float4 v = make_float4(0.f, 0.f, 0.f, 0.f);
            if (k < NK) v = *(const float4*)(W + (size_t)k * DM + ds0 + dq * 4);
            sw[k * 16 + (dq ^ (k >> 3))] = v;
        }
        __syncthreads();

        // ---- GEMM micro-tile: per d-quad, 16 b128 LDS reads feed 256 fmac ----
        for (int dq = 0; dq < 16; ++dq) {
            float4 a[8];
#pragma unroll
            for (int i = 0; i < 8; ++i) a[i] = sxa[(typ * 8 + i) * 16 + (dq ^ typ)];
#pragma unroll
            for (int j = 0; j < 8; ++j) {
                const float4 bv = sw[(txk * 8 + j) * 16 + (dq ^ txk)];
#pragma unroll
                for (int i = 0; i < 8; ++i) {
                    acc[i][j] = fmaf(a[i].x, bv.x, acc[i][j]);
                    acc[i][j] = fmaf(a[i].y, bv.y, acc[i][j]);
                    acc[i][j] = fmaf(a[i].z, bv.z, acc[i][j]);
                    acc[i][j] = fmaf(a[i].w, bv.w, acc[i][j]);
                }
            }
        }
        __syncthreads();
    }

    // ---- split-K accumulate (device-scope fp32 atomics; 8 adds/element) ----
#pragma unroll
    for (int i = 0; i < 8; ++i) {
        const size_t p = (size_t)pos0 + typ * 8 + i;
#pragma unroll
        for (int j = 0; j < 8; ++j) {
            const int k = txk * 8 + j;
            if (k < NK) atomicAdd(&z[p * NKP + k], acc[i][j]);
        }
    }
}

// ---------------- kernel 3: Cayley transform + block-Frobenius ---------------
// One wave per position; 16x16 Gauss-Jordan entirely in registers via shfl.
// Lane l: column j = l&15, row-group g = l>>4; lane owns rows i = 4r+g, r=0..3.
// I+A has SPD symmetric part (= I) -> pivot-free GJ is stable.
__global__ void cayley(const float* __restrict__ z, const float* __restrict__ bvec,
                       float* __restrict__ out) {
    const int t = threadIdx.x;
    const int wave = t >> 6;
    const int l = t & 63;
    const int pos = blockIdx.x * 4 + wave;
    const int j = l & 15;
    const int g = l >> 4;

    float m[4], x[4];
#pragma unroll
    for (int r = 0; r < 4; ++r) {
        const int i = 4 * r + g;
        float a;
        if (i < j) {
            const int k = (i * (31 - i)) / 2 + (j - i - 1);
            a = z[(size_t)pos * NKP + k] + bvec[k];
        } else if (i > j) {
            const int k = (j * (31 - j)) / 2 + (i - j - 1);
            a = -(z[(size_t)pos * NKP + k] + bvec[k]);
        } else {
            a = 0.f;
        }
        const float d = (i == j) ? 1.f : 0.f;
        m[r] = d + a;   // M = I + A
        x[r] = d - a;   // X = I - A  (becomes Q after solve)
    }

#pragma unroll
    for (int k = 0; k < 16; ++k) {
        const int rr = k >> 2;
        const int src_row = (k & 3) << 4;          // lanes holding row k
        const float mk  = __shfl(m[rr], src_row | j, 64);   // M[k][j]
        const float xk  = __shfl(x[rr], src_row | j, 64);   // X[k][j]
        const float mkk = __shfl(m[rr], src_row | k, 64);   // M[k][k]
        const float rk = 1.0f / mkk;
#pragma unroll
        for (int r = 0; r < 4; ++r) {
            const float mik = __shfl(m[r], (g << 4) | k, 64);  // M[4r+g][k]
            const float f = (4 * r + g == k) ? 0.f : mik * rk;
            m[r] = fmaf(-f, mk, m[r]);
            x[r] = fmaf(-f, xk, x[r]);
        }
    }

    float h[4];
#pragma unroll
    for (int r = 0; r < 4; ++r) {
        const int i = 4 * r + g;
        const float mdiag = __shfl(m[r], (g << 4) | i, 64);  // M[i][i]
        const float q = x[r] / mdiag;                        // Q[i][j]
        float s = q * q;
        s += __shfl_xor(s, 1, 64);    // sum over column pair (s2)
        s += __shfl_xor(s, 16, 64);   // sum over row pair (s1)
        h[r] = s * 0.5f;
    }
    if (((j & 1) == 0) && ((g & 1) == 0)) {
        const int col = j >> 1;
#pragma unroll
        for (int r = 0; r < 4; ++r) {
            const int row = 2 * r + (g >> 1);
            out[(size_t)pos * 64 + row * 8 + col] = h[r];
        }
    }
}

// ---------------- launcher ---------------------------------------------------
extern "C" void kernel_launch(void* const* d_in, const int* in_sizes, int n_in,
                              void* d_out, int out_size, void* d_ws, size_t ws_size,
                              hipStream_t stream) {
    const float* streams = (const float*)d_in[0];  // [2,4096,8,2048] fp32
    const float* W       = (const float*)d_in[1];  // [120,2048] fp32
    const float* bvec    = (const float*)d_in[2];  // [120] fp32
    float* out = (float*)d_out;                    // [2,4096,8,8] fp32
    float* z   = (float*)d_ws;                     // [8192,128] fp32 accumulator

    // zero 8192*128 floats = 262144 float4
    zero_ws<<<1024, 256, 0, stream>>>((float4*)d_ws);
    mean_proj<<<512, 256, 0, stream>>>(streams, W, z);
    cayley<<<2048, 256, 0, stream>>>(z, bvec, out);
}